// Round 1
// baseline (451.515 us; speedup 1.0000x reference)
//
#include <hip/hip_runtime.h>
#include <math.h>

#define KQ   32768
#define CC   100
#define BB   1024
#define DD   128
#define NTOT (BB + KQ)    // 33792
#define N1   (BB + CC)    // 1124

#define NC2  132          // branch-2 column chunks (span 256 = 4 subtiles of 64); 132*256 = 33792
#define NC1  18           // branch-1 column chunks (span 64); 18*64 = 1152 >= 1124

__device__ __constant__ float ALPHA_C = 0.05f;
#define INV_T  (1.0f / 0.07f)
#define EPSV   1e-12f

// ---------------- histogram ----------------
__global__ void hist_k(const int* __restrict__ labels, int* __restrict__ cntAll,
                       int* __restrict__ cntBatch) {
    int t = blockIdx.x * blockDim.x + threadIdx.x;
    if (t < NTOT) {
        int l = labels[t];
        atomicAdd(&cntAll[l], 1);
        if (t < BB) atomicAdd(&cntBatch[l], 1);
    }
}

// ---------------- branch-2 GEMM: anchors x all features ----------------
// grid (16, NC2), block 256. Each block: 64 rows x 256 cols (4 subtiles of 64), K=128 in 2 halves.
__global__ __launch_bounds__(256) void gemm2_k(
    const float* __restrict__ feats, const int* __restrict__ labels,
    const int* __restrict__ cntAll, float* __restrict__ pS, float* __restrict__ pN) {
    __shared__ float Asm[2][64][68];
    __shared__ float Bsm[64][68];
    __shared__ int   labR[64];
    __shared__ int   labC[64];
    __shared__ float rcpN[64], rcpM[64];

    const int tid = threadIdx.x;
    const int tx = tid & 15, ty = tid >> 4;
    const int r0 = blockIdx.x * 64;
    const int c0 = blockIdx.y * 256;
    const int ch = blockIdx.y;

    // load A tile: 64 rows x 128 floats = 2048 float4 (8 per thread)
#pragma unroll
    for (int s = 0; s < 8; ++s) {
        int f = tid + 256 * s;
        int row = f >> 5;
        int k4 = f & 31;
        float4 v = *(const float4*)&feats[(size_t)(r0 + row) * DD + k4 * 4];
        int h = k4 >> 4;
        int kk = (k4 & 15) * 4;
        *(float4*)&Asm[h][row][kk] = v;
    }
    if (tid < 64) labR[tid] = labels[r0 + tid];
    __syncthreads();

    int lr[4], gr[4];
#pragma unroll
    for (int i = 0; i < 4; ++i) { gr[i] = r0 + ty + 16 * i; lr[i] = labR[ty + 16 * i]; }

    float sS[4] = {0.f, 0.f, 0.f, 0.f};
    float sN[4] = {0.f, 0.f, 0.f, 0.f};

    for (int sub = 0; sub < 4; ++sub) {
        const int cb = c0 + sub * 64;
        float acc[4][4];
#pragma unroll
        for (int i = 0; i < 4; ++i)
#pragma unroll
            for (int j = 0; j < 4; ++j) acc[i][j] = 0.f;

        for (int h = 0; h < 2; ++h) {
            __syncthreads();
            // load B half: 64 cols x 64 floats = 1024 float4 (4 per thread)
#pragma unroll
            for (int s = 0; s < 4; ++s) {
                int f = tid + 256 * s;
                int col = f >> 4;
                int k4 = f & 15;
                float4 v = *(const float4*)&feats[(size_t)(cb + col) * DD + h * 64 + k4 * 4];
                *(float4*)&Bsm[col][k4 * 4] = v;
            }
            if (h == 0 && tid < 64) {
                int lc = labels[cb + tid];
                labC[tid] = lc;
                float cnt = (float)cntAll[lc];
                rcpN[tid] = 1.0f / cnt;
                rcpM[tid] = 1.0f / (cnt - ALPHA_C);
            }
            __syncthreads();
#pragma unroll
            for (int k4 = 0; k4 < 16; ++k4) {
                float4 a[4], b[4];
#pragma unroll
                for (int i = 0; i < 4; ++i) a[i] = *(const float4*)&Asm[h][ty + 16 * i][k4 * 4];
#pragma unroll
                for (int j = 0; j < 4; ++j) b[j] = *(const float4*)&Bsm[tx + 16 * j][k4 * 4];
#pragma unroll
                for (int i = 0; i < 4; ++i)
#pragma unroll
                    for (int j = 0; j < 4; ++j)
                        acc[i][j] += a[i].x * b[j].x + a[i].y * b[j].y +
                                     a[i].z * b[j].z + a[i].w * b[j].w;
            }
        }
        // epilogue for this subtile
#pragma unroll
        for (int j = 0; j < 4; ++j) {
            int c = tx + 16 * j;
            int gc = cb + c;
            int lc = labC[c];
            float rn = rcpN[c], rm = rcpM[c];
#pragma unroll
            for (int i = 0; i < 4; ++i) {
                if (gc == gr[i]) continue;  // diagonal masked
                float raw = acc[i][j] * INV_T;
                float e = __expf(raw - INV_T);
                bool m = (lc == lr[i]);
                sS[i] += e * (m ? rm : rn);
                if (m) sN[i] += raw;
            }
        }
    }
    // reduce across tx (16 consecutive lanes share the same rows)
#pragma unroll
    for (int i = 0; i < 4; ++i) {
        for (int off = 8; off > 0; off >>= 1) {
            sS[i] += __shfl_down(sS[i], off, 16);
            sN[i] += __shfl_down(sN[i], off, 16);
        }
    }
    if (tx == 0) {
#pragma unroll
        for (int i = 0; i < 4; ++i) {
            pS[(size_t)ch * BB + r0 + ty + 16 * i] = sS[i];
            pN[(size_t)ch * BB + r0 + ty + 16 * i] = sN[i];
        }
    }
}

// ---------------- branch-1 GEMM: anchors x [batch, centers] ----------------
// grid (16, NC1), block 256. Each block: 64 rows x 64 cols, K=128 in 2 halves.
__global__ __launch_bounds__(256) void gemm1_k(
    const float* __restrict__ feats, const float* __restrict__ centers,
    const int* __restrict__ labels, const int* __restrict__ cntBatch,
    float* __restrict__ pS, float* __restrict__ pN) {
    __shared__ float Asm[2][64][68];
    __shared__ float Bsm[64][68];
    __shared__ int   labR[64];
    __shared__ int   labC[64];
    __shared__ float rcpN[64], rcpM[64];

    const int tid = threadIdx.x;
    const int tx = tid & 15, ty = tid >> 4;
    const int r0 = blockIdx.x * 64;
    const int cb = blockIdx.y * 64;
    const int ch = blockIdx.y;

#pragma unroll
    for (int s = 0; s < 8; ++s) {
        int f = tid + 256 * s;
        int row = f >> 5;
        int k4 = f & 31;
        float4 v = *(const float4*)&feats[(size_t)(r0 + row) * DD + k4 * 4];
        int h = k4 >> 4;
        int kk = (k4 & 15) * 4;
        *(float4*)&Asm[h][row][kk] = v;
    }
    if (tid < 64) labR[tid] = labels[r0 + tid];
    __syncthreads();

    int lr[4], gr[4];
#pragma unroll
    for (int i = 0; i < 4; ++i) { gr[i] = r0 + ty + 16 * i; lr[i] = labR[ty + 16 * i]; }

    float sS[4] = {0.f, 0.f, 0.f, 0.f};
    float sN[4] = {0.f, 0.f, 0.f, 0.f};

    float acc[4][4];
#pragma unroll
    for (int i = 0; i < 4; ++i)
#pragma unroll
        for (int j = 0; j < 4; ++j) acc[i][j] = 0.f;

    for (int h = 0; h < 2; ++h) {
        __syncthreads();
#pragma unroll
        for (int s = 0; s < 4; ++s) {
            int f = tid + 256 * s;
            int col = f >> 4;
            int k4 = f & 15;
            int gc = cb + col;
            float4 v = make_float4(0.f, 0.f, 0.f, 0.f);
            if (gc < BB)      v = *(const float4*)&feats[(size_t)gc * DD + h * 64 + k4 * 4];
            else if (gc < N1) v = *(const float4*)&centers[(size_t)(gc - BB) * DD + h * 64 + k4 * 4];
            *(float4*)&Bsm[col][k4 * 4] = v;
        }
        if (h == 0 && tid < 64) {
            int gc = cb + tid;
            int lc;
            float rn, rm;
            if (gc < BB)      lc = labels[gc];
            else if (gc < N1) lc = gc - BB;
            else              lc = -1;
            if (lc >= 0) {
                float c1 = (float)(cntBatch[lc] + 1);  // cls_count1
                rn = 1.0f / c1;
                rm = 1.0f / (c1 - 1.0f);  // only selected when match => cntBatch>=1
            } else { rn = 0.f; rm = 0.f; }
            labC[tid] = lc; rcpN[tid] = rn; rcpM[tid] = rm;
        }
        __syncthreads();
#pragma unroll
        for (int k4 = 0; k4 < 16; ++k4) {
            float4 a[4], b[4];
#pragma unroll
            for (int i = 0; i < 4; ++i) a[i] = *(const float4*)&Asm[h][ty + 16 * i][k4 * 4];
#pragma unroll
            for (int j = 0; j < 4; ++j) b[j] = *(const float4*)&Bsm[tx + 16 * j][k4 * 4];
#pragma unroll
            for (int i = 0; i < 4; ++i)
#pragma unroll
                for (int j = 0; j < 4; ++j)
                    acc[i][j] += a[i].x * b[j].x + a[i].y * b[j].y +
                                 a[i].z * b[j].z + a[i].w * b[j].w;
        }
    }
#pragma unroll
    for (int j = 0; j < 4; ++j) {
        int c = tx + 16 * j;
        int gc = cb + c;
        int lc = labC[c];
        float rn = rcpN[c], rm = rcpM[c];
#pragma unroll
        for (int i = 0; i < 4; ++i) {
            if (gc == gr[i]) continue;  // diagonal (only possible for gc < BB)
            float raw = acc[i][j] * INV_T;
            float e = __expf(raw - INV_T);
            bool m = (lc == lr[i]);
            sS[i] += e * (m ? rm : rn);
            if (m) sN[i] += raw;
        }
    }
#pragma unroll
    for (int i = 0; i < 4; ++i) {
        for (int off = 8; off > 0; off >>= 1) {
            sS[i] += __shfl_down(sS[i], off, 16);
            sN[i] += __shfl_down(sN[i], off, 16);
        }
    }
    if (tx == 0) {
#pragma unroll
        for (int i = 0; i < 4; ++i) {
            pS[(size_t)ch * BB + r0 + ty + 16 * i] = sS[i];
            pN[(size_t)ch * BB + r0 + ty + 16 * i] = sN[i];
        }
    }
}

// ---------------- finalize per-row ----------------
__global__ void finalize_k(const float* __restrict__ sup, const int* __restrict__ labels,
                           const int* __restrict__ cntAll, const int* __restrict__ cntBatch,
                           const float* __restrict__ p2S, const float* __restrict__ p2N,
                           const float* __restrict__ p1S, const float* __restrict__ p1N,
                           float* __restrict__ rowloss) {
    int i = blockIdx.x * blockDim.x + threadIdx.x;
    if (i >= BB) return;
    int li = labels[i];

    float S2 = 0.f, N2 = 0.f;
    for (int c = 0; c < NC2; ++c) { S2 += p2S[(size_t)c * BB + i]; N2 += p2N[(size_t)c * BB + i]; }
    float S1 = 0.f, Nn1 = 0.f;
    for (int c = 0; c < NC1; ++c) { S1 += p1S[(size_t)c * BB + i]; Nn1 += p1N[(size_t)c * BB + i]; }

    // sup-logits part of branch 2 (SUPT = 1)
    const float* srow = &sup[(size_t)i * CC];
    for (int c = 0; c < CC; ++c) {
        float raw = srow[c];
        float w = (float)cntAll[c] - (c == li ? 1.0f : 0.0f);
        S2 += __expf(raw - INV_T) / w;
    }
    float num2 = srow[li] + ALPHA_C * N2;
    float cA = (float)cntAll[li];
    float msum2 = 1.0f + ALPHA_C * (cA - 1.0f);
    float loss2 = -(num2 / msum2 - INV_T - logf(S2 + EPSV));

    float msum1 = (float)cntBatch[li];  // = cls_count1[li] - 1
    float loss1 = -(Nn1 / msum1 - INV_T - logf(S1 + EPSV));

    rowloss[i] = loss1 + loss2;
}

// ---------------- final scalar reduce ----------------
__global__ void reduce_k(const float* __restrict__ rowloss, float* __restrict__ out) {
    __shared__ float buf[4];
    int t = threadIdx.x;
    float s = rowloss[t] + rowloss[t + 256] + rowloss[t + 512] + rowloss[t + 768];
    for (int off = 32; off > 0; off >>= 1) s += __shfl_down(s, off, 64);
    if ((t & 63) == 0) buf[t >> 6] = s;
    __syncthreads();
    if (t == 0) out[0] = (buf[0] + buf[1] + buf[2] + buf[3]) / (float)BB;
}

extern "C" void kernel_launch(void* const* d_in, const int* in_sizes, int n_in,
                              void* d_out, int out_size, void* d_ws, size_t ws_size,
                              hipStream_t stream) {
    const float* feats   = (const float*)d_in[0];
    const float* sup     = (const float*)d_in[1];
    const float* centers = (const float*)d_in[2];
    const int*   labels  = (const int*)d_in[3];
    float* out = (float*)d_out;
    float* ws  = (float*)d_ws;

    int*   cntAll   = (int*)ws;              // 128 ints
    int*   cntBatch = (int*)(ws + 128);      // 128 ints
    float* p2S = ws + 256;
    float* p2N = p2S + (size_t)NC2 * BB;
    float* p1S = p2N + (size_t)NC2 * BB;
    float* p1N = p1S + (size_t)NC1 * BB;
    float* rowloss = p1N + (size_t)NC1 * BB;

    hipMemsetAsync(ws, 0, 256 * sizeof(float), stream);
    hist_k<<<(NTOT + 255) / 256, 256, 0, stream>>>(labels, cntAll, cntBatch);
    gemm2_k<<<dim3(16, NC2), 256, 0, stream>>>(feats, labels, cntAll, p2S, p2N);
    gemm1_k<<<dim3(16, NC1), 256, 0, stream>>>(feats, centers, labels, cntBatch, p1S, p1N);
    finalize_k<<<4, 256, 0, stream>>>(sup, labels, cntAll, cntBatch, p2S, p2N, p1S, p1N, rowloss);
    reduce_k<<<1, 256, 0, stream>>>(rowloss, out);
}

// Round 2
// 203.777 us; speedup vs baseline: 2.2157x; 2.2157x over previous
//
#include <hip/hip_runtime.h>
#include <math.h>

#define KQ   32768
#define CC   100
#define BB   1024
#define DD   128
#define NTOT (BB + KQ)        // 33792
#define NROWS_X 33920         // 33792 feats + 100 centers + 28 zero pad
#define CB_CENT 1056          // first center cb (33792/32)
#define NCB  1060             // total 32-row blocks in X2
#define NC2G 132              // gemm2 col groups (8 cb = 256 cols each)
#define NC1G 9                // gemm1 col groups (4 cb = 128 cols each)

#define INV_T  14.285714285714286f
#define ALPHA  0.05f
#define EPSV   1e-12f

typedef __attribute__((ext_vector_type(8)))  short          short8;
typedef __attribute__((ext_vector_type(8)))  unsigned short ushort8;
typedef __attribute__((ext_vector_type(16))) float          float16;

// X2 layout: per 32-row block cb (16384 B):
//   [h=0 hi | h=1 lo][ks 0..7][lane 0..63][16 B]
// where element (row r, k): cb=r>>5, ks=k>>4, lane=(r&31)+32*((k>>3)&1), j=k&7.
// This is exactly the 32x32x16 MFMA A/B operand layout -> frag load = one
// coalesced 16B/lane global load.

__device__ __forceinline__ unsigned short f2bf_rne(float f) {
    unsigned int u = __float_as_uint(f);
    return (unsigned short)((u + 0x7FFFu + ((u >> 16) & 1u)) >> 16);
}

// ---------------- preprocess: fp32 -> split hi/lo bf16, MFMA-tiled ----------------
__global__ __launch_bounds__(256) void prep_k(const float* __restrict__ feats,
                                              const float* __restrict__ centers,
                                              unsigned short* __restrict__ X2) {
    int t = blockIdx.x * 256 + threadIdx.x;
    if (t >= NROWS_X * 16) return;
    int r = t >> 4, kg = t & 15;
    float v[8];
    if (r < NTOT) {
        const float* p = &feats[(size_t)r * DD + kg * 8];
        float4 a = *(const float4*)p, b = *(const float4*)(p + 4);
        v[0]=a.x; v[1]=a.y; v[2]=a.z; v[3]=a.w; v[4]=b.x; v[5]=b.y; v[6]=b.z; v[7]=b.w;
    } else if (r < NTOT + CC) {
        const float* p = &centers[(size_t)(r - NTOT) * DD + kg * 8];
        float4 a = *(const float4*)p, b = *(const float4*)(p + 4);
        v[0]=a.x; v[1]=a.y; v[2]=a.z; v[3]=a.w; v[4]=b.x; v[5]=b.y; v[6]=b.z; v[7]=b.w;
    } else {
#pragma unroll
        for (int j = 0; j < 8; ++j) v[j] = 0.0f;
    }
    ushort8 H, L;
#pragma unroll
    for (int j = 0; j < 8; ++j) {
        unsigned short hb = f2bf_rne(v[j]);
        float hf = __uint_as_float(((unsigned int)hb) << 16);
        unsigned short lb = f2bf_rne(v[j] - hf);
        H[j] = hb; L[j] = lb;
    }
    int cb = r >> 5, ks = kg >> 1, lh = kg & 1;
    int lanei = (r & 31) + 32 * lh;
    size_t base = (size_t)cb * 16384 + (size_t)ks * 1024 + (size_t)lanei * 16;
    *(ushort8*)((char*)X2 + base)        = H;
    *(ushort8*)((char*)X2 + base + 8192) = L;
}

// ---------------- histogram ----------------
__global__ void hist_k(const int* __restrict__ labels, int* __restrict__ cntAll,
                       int* __restrict__ cntBatch) {
    int t = blockIdx.x * blockDim.x + threadIdx.x;
    if (t < NTOT) {
        int l = labels[t];
        atomicAdd(&cntAll[l], 1);
        if (t < BB) atomicAdd(&cntBatch[l], 1);
    }
}

// ---------------- branch-2 MFMA GEMM: anchors x all features ----------------
// grid (8, NC2G), block 256 = 4 waves. Block: 128 rows x 256 cols. Wave: 32 rows.
__global__ __launch_bounds__(256) void gemm2_k(
    const unsigned short* __restrict__ X2, const int* __restrict__ labels,
    const int* __restrict__ cntAll, float* __restrict__ pS, float* __restrict__ pN) {
    const int tid  = threadIdx.x;
    const int lane = tid & 63, w = tid >> 6;
    const int half = lane >> 5, ln = lane & 31;
    const int rt = blockIdx.x, cg = blockIdx.y;
    const int rb = rt * 4 + w;
    const char* Xb = (const char*)X2;

    // A fragments: resident for whole block. 8 ks x (hi,lo) = 64 VGPRs.
    short8 Ah[8], Al[8];
    {
        size_t abase = (size_t)rb * 16384 + (size_t)lane * 16;
#pragma unroll
        for (int ks = 0; ks < 8; ++ks) {
            Ah[ks] = *(const short8*)(Xb + abase + (size_t)ks * 1024);
            Al[ks] = *(const short8*)(Xb + abase + 8192 + (size_t)ks * 1024);
        }
    }
    const int growbase = rt * 128 + w * 32;
    int rlab[16];
#pragma unroll
    for (int reg = 0; reg < 16; ++reg) {
        int ro = (reg & 3) + 8 * (reg >> 2) + 4 * half;
        rlab[reg] = labels[growbase + ro];
    }
    float sS[16], sN[16];
#pragma unroll
    for (int reg = 0; reg < 16; ++reg) { sS[reg] = 0.f; sN[reg] = 0.f; }

    for (int i = 0; i < 8; ++i) {
        const int cb = cg * 8 + i;
        const int ccol = cb * 32 + ln;
        int lc = labels[ccol];
        float cnt = (float)cntAll[lc];
        float rn = __builtin_amdgcn_rcpf(cnt);
        float rm = __builtin_amdgcn_rcpf(cnt - ALPHA);

        const size_t bbase = (size_t)cb * 16384 + (size_t)lane * 16;
        float16 acc;
#pragma unroll
        for (int reg = 0; reg < 16; ++reg) acc[reg] = 0.f;
#pragma unroll
        for (int ks = 0; ks < 8; ++ks) {
            short8 Bh = *(const short8*)(Xb + bbase + (size_t)ks * 1024);
            short8 Bl = *(const short8*)(Xb + bbase + 8192 + (size_t)ks * 1024);
            acc = __builtin_amdgcn_mfma_f32_32x32x16_bf16(Ah[ks], Bh, acc, 0, 0, 0);
            acc = __builtin_amdgcn_mfma_f32_32x32x16_bf16(Ah[ks], Bl, acc, 0, 0, 0);
            acc = __builtin_amdgcn_mfma_f32_32x32x16_bf16(Al[ks], Bh, acc, 0, 0, 0);
        }
#pragma unroll
        for (int reg = 0; reg < 16; ++reg) {
            int ro = (reg & 3) + 8 * (reg >> 2) + 4 * half;
            int grow = growbase + ro;
            float raw = acc[reg] * INV_T;
            float e = __expf(raw - INV_T);
            bool m = (lc == rlab[reg]);
            bool diag = (ccol == grow);
            float wgt = diag ? 0.0f : (m ? rm : rn);
            sS[reg] += e * wgt;
            sN[reg] += (m && !diag) ? raw : 0.0f;
        }
    }
    // reduce across the 32 lanes of each half (cols), then store per-row partials
#pragma unroll
    for (int reg = 0; reg < 16; ++reg) {
        float a = sS[reg], b = sN[reg];
#pragma unroll
        for (int off = 1; off < 32; off <<= 1) {
            a += __shfl_xor(a, off, 64);
            b += __shfl_xor(b, off, 64);
        }
        if (ln == 0) {
            int ro = (reg & 3) + 8 * (reg >> 2) + 4 * half;
            int grow = growbase + ro;
            pS[(size_t)cg * BB + grow] = a;
            pN[(size_t)cg * BB + grow] = b;
        }
    }
}

// ---------------- branch-1 MFMA GEMM: anchors x [batch, centers] ----------------
// grid (8, NC1G), block 256 = 4 waves. Groups 0..7: batch cols; group 8: center cbs.
__global__ __launch_bounds__(256) void gemm1_k(
    const unsigned short* __restrict__ X2, const int* __restrict__ labels,
    const int* __restrict__ cntBatch, float* __restrict__ pS, float* __restrict__ pN) {
    const int tid  = threadIdx.x;
    const int lane = tid & 63, w = tid >> 6;
    const int half = lane >> 5, ln = lane & 31;
    const int rt = blockIdx.x, cg = blockIdx.y;
    const int rb = rt * 4 + w;
    const char* Xb = (const char*)X2;

    short8 Ah[8], Al[8];
    {
        size_t abase = (size_t)rb * 16384 + (size_t)lane * 16;
#pragma unroll
        for (int ks = 0; ks < 8; ++ks) {
            Ah[ks] = *(const short8*)(Xb + abase + (size_t)ks * 1024);
            Al[ks] = *(const short8*)(Xb + abase + 8192 + (size_t)ks * 1024);
        }
    }
    const int growbase = rt * 128 + w * 32;
    int rlab[16];
#pragma unroll
    for (int reg = 0; reg < 16; ++reg) {
        int ro = (reg & 3) + 8 * (reg >> 2) + 4 * half;
        rlab[reg] = labels[growbase + ro];
    }
    float sS[16], sN[16];
#pragma unroll
    for (int reg = 0; reg < 16; ++reg) { sS[reg] = 0.f; sN[reg] = 0.f; }

    for (int i = 0; i < 4; ++i) {
        const int cb = (cg < 8) ? (cg * 4 + i) : (CB_CENT + i);
        const int ccol = cb * 32 + ln;
        int lc;
        if (cg < 8) lc = labels[ccol];
        else { int c = ccol - NTOT; lc = (c < CC) ? c : -1; }
        float rn, rm;
        if (lc >= 0) {
            float c1 = (float)(cntBatch[lc] + 1);            // cls_count1
            rn = __builtin_amdgcn_rcpf(c1);
            rm = __builtin_amdgcn_rcpf(c1 - 1.0f);           // only selected when a match exists
        } else { rn = 0.f; rm = 0.f; }

        const size_t bbase = (size_t)cb * 16384 + (size_t)lane * 16;
        float16 acc;
#pragma unroll
        for (int reg = 0; reg < 16; ++reg) acc[reg] = 0.f;
#pragma unroll
        for (int ks = 0; ks < 8; ++ks) {
            short8 Bh = *(const short8*)(Xb + bbase + (size_t)ks * 1024);
            short8 Bl = *(const short8*)(Xb + bbase + 8192 + (size_t)ks * 1024);
            acc = __builtin_amdgcn_mfma_f32_32x32x16_bf16(Ah[ks], Bh, acc, 0, 0, 0);
            acc = __builtin_amdgcn_mfma_f32_32x32x16_bf16(Ah[ks], Bl, acc, 0, 0, 0);
            acc = __builtin_amdgcn_mfma_f32_32x32x16_bf16(Al[ks], Bh, acc, 0, 0, 0);
        }
#pragma unroll
        for (int reg = 0; reg < 16; ++reg) {
            int ro = (reg & 3) + 8 * (reg >> 2) + 4 * half;
            int grow = growbase + ro;
            float raw = acc[reg] * INV_T;
            float e = __expf(raw - INV_T);
            bool m = (lc == rlab[reg]);
            bool diag = (cg < 8) && (ccol == grow);
            float wgt = diag ? 0.0f : (m ? rm : rn);
            sS[reg] += e * wgt;
            sN[reg] += (m && !diag) ? raw : 0.0f;
        }
    }
#pragma unroll
    for (int reg = 0; reg < 16; ++reg) {
        float a = sS[reg], b = sN[reg];
#pragma unroll
        for (int off = 1; off < 32; off <<= 1) {
            a += __shfl_xor(a, off, 64);
            b += __shfl_xor(b, off, 64);
        }
        if (ln == 0) {
            int ro = (reg & 3) + 8 * (reg >> 2) + 4 * half;
            int grow = growbase + ro;
            pS[(size_t)cg * BB + grow] = a;
            pN[(size_t)cg * BB + grow] = b;
        }
    }
}

// ---------------- finalize per-row ----------------
__global__ void finalize_k(const float* __restrict__ sup, const int* __restrict__ labels,
                           const int* __restrict__ cntAll, const int* __restrict__ cntBatch,
                           const float* __restrict__ p2S, const float* __restrict__ p2N,
                           const float* __restrict__ p1S, const float* __restrict__ p1N,
                           float* __restrict__ rowloss) {
    int i = blockIdx.x * blockDim.x + threadIdx.x;
    if (i >= BB) return;
    int li = labels[i];

    float S2 = 0.f, N2 = 0.f;
    for (int c = 0; c < NC2G; ++c) { S2 += p2S[(size_t)c * BB + i]; N2 += p2N[(size_t)c * BB + i]; }
    float S1 = 0.f, N1 = 0.f;
    for (int c = 0; c < NC1G; ++c) { S1 += p1S[(size_t)c * BB + i]; N1 += p1N[(size_t)c * BB + i]; }

    const float* srow = &sup[(size_t)i * CC];
    for (int c = 0; c < CC; ++c) {
        float raw = srow[c];
        float wv = (float)cntAll[c] - (c == li ? 1.0f : 0.0f);
        S2 += __expf(raw - INV_T) / wv;
    }
    float num2 = srow[li] + ALPHA * N2;
    float cA = (float)cntAll[li];
    float msum2 = 1.0f + ALPHA * (cA - 1.0f);
    float loss2 = -(num2 / msum2 - INV_T - logf(S2 + EPSV));

    float msum1 = (float)cntBatch[li];
    float loss1 = -(N1 / msum1 - INV_T - logf(S1 + EPSV));

    rowloss[i] = loss1 + loss2;
}

// ---------------- final scalar reduce ----------------
__global__ void reduce_k(const float* __restrict__ rowloss, float* __restrict__ out) {
    __shared__ float buf[4];
    int t = threadIdx.x;
    float s = rowloss[t] + rowloss[t + 256] + rowloss[t + 512] + rowloss[t + 768];
    for (int off = 32; off > 0; off >>= 1) s += __shfl_down(s, off, 64);
    if ((t & 63) == 0) buf[t >> 6] = s;
    __syncthreads();
    if (t == 0) out[0] = (buf[0] + buf[1] + buf[2] + buf[3]) / (float)BB;
}

extern "C" void kernel_launch(void* const* d_in, const int* in_sizes, int n_in,
                              void* d_out, int out_size, void* d_ws, size_t ws_size,
                              hipStream_t stream) {
    const float* feats   = (const float*)d_in[0];
    const float* sup     = (const float*)d_in[1];
    const float* centers = (const float*)d_in[2];
    const int*   labels  = (const int*)d_in[3];
    float* out = (float*)d_out;
    char*  wsb = (char*)d_ws;

    // ws layout (bytes)
    const size_t X2_BYTES = (size_t)NCB * 16384;         // 17,367,040
    unsigned short* X2 = (unsigned short*)wsb;
    int* cntAll   = (int*)(wsb + X2_BYTES);              // 128 ints
    int* cntBatch = cntAll + 128;                        // 128 ints
    float* p2S = (float*)(wsb + X2_BYTES + 1024);
    float* p2N = p2S + (size_t)NC2G * BB;
    float* p1S = p2N + (size_t)NC2G * BB;
    float* p1N = p1S + (size_t)NC1G * BB;
    float* rowloss = p1N + (size_t)NC1G * BB;

    hipMemsetAsync(cntAll, 0, 1024, stream);
    prep_k<<<(NROWS_X * 16 + 255) / 256, 256, 0, stream>>>(feats, centers, X2);
    hist_k<<<(NTOT + 255) / 256, 256, 0, stream>>>(labels, cntAll, cntBatch);
    gemm2_k<<<dim3(8, NC2G), 256, 0, stream>>>(X2, labels, cntAll, p2S, p2N);
    gemm1_k<<<dim3(8, NC1G), 256, 0, stream>>>(X2, labels, cntBatch, p1S, p1N);
    finalize_k<<<4, 256, 0, stream>>>(sup, labels, cntAll, cntBatch, p2S, p2N, p1S, p1N, rowloss);
    reduce_k<<<1, 256, 0, stream>>>(rowloss, out);
}